// Round 8
// baseline (573.278 us; speedup 1.0000x reference)
//
#include <hip/hip_runtime.h>

// Problem constants (match reference setup_inputs)
#define BB 16
#define NN 2048
#define EE 32768
#define DD 256
#define RR 8
#define LL 2
#define BUCKETS (RR * NN)   // 16384 buckets per batch
#define TM 64               // GEMM m-tile

typedef unsigned short u16;
typedef __attribute__((__ext_vector_type__(8))) __bf16 bfx8;   // MFMA A/B frag
typedef __attribute__((__ext_vector_type__(16))) float fx16;   // MFMA acc
typedef __attribute__((__ext_vector_type__(2))) float f32x2;   // v_pk_add_f32

__device__ __forceinline__ float blo(unsigned u){ union{unsigned x;float f;}c; c.x=u<<16; return c.f; }
__device__ __forceinline__ float bhi(unsigned u){ union{unsigned x;float f;}c; c.x=u&0xffff0000u; return c.f; }
__device__ __forceinline__ u16 f2bf(float f){ union{float f;unsigned u;}x; x.f=f;
    return (u16)((x.u + 0x7FFFu + ((x.u>>16)&1u))>>16); }           // RNE
__device__ __forceinline__ unsigned pk2(float a, float b){
    return (unsigned)f2bf(a) | ((unsigned)f2bf(b)<<16); }
// packed accumulate: 8 f32x2 lanespace, 1 shift + 1 and + 1 v_pk_add_f32 per uint
__device__ __forceinline__ void acc8pk(f32x2* a, uint4 p0, uint4 p1) {
    f32x2 v;
    v.x=blo(p0.x); v.y=bhi(p0.x); a[0]+=v;
    v.x=blo(p0.y); v.y=bhi(p0.y); a[1]+=v;
    v.x=blo(p0.z); v.y=bhi(p0.z); a[2]+=v;
    v.x=blo(p0.w); v.y=bhi(p0.w); a[3]+=v;
    v.x=blo(p1.x); v.y=bhi(p1.x); a[4]+=v;
    v.x=blo(p1.y); v.y=bhi(p1.y); a[5]+=v;
    v.x=blo(p1.z); v.y=bhi(p1.z); a[6]+=v;
    v.x=blo(p1.w); v.y=bhi(p1.w); a[7]+=v;
}

// ---------------------------------------------------------------------------
// prep0: (a) weight prep into MFMA-B fragment order (144 blocks)
//        Wf[ls][kt(8)][nt8(8)][ks2(2)][fl(64)][e(8)] bf16,
//        n = nt8*32+(fl&31), k = kt*32+ks2*16+(fl>>5)*8+e, val = Wsrc[k][n]
//        (b) zero counts (remaining blocks)
// ---------------------------------------------------------------------------
__global__ __launch_bounds__(256) void prep0(const float* __restrict__ W,
                                             const float* __restrict__ Wroot,
                                             u16* __restrict__ Wf,
                                             int* __restrict__ counts, int bc)
{
    int t = threadIdx.x;
    if (blockIdx.x < 8 * LL * 9) {
        __shared__ float tl[32][257];   // [k][n], padded
        int kt = blockIdx.x & 7, ls = blockIdx.x >> 3;
        int l = ls / 9, seg = ls - l * 9;
        const float* src = (seg < 8) ? W + (size_t)(l * RR + seg) * DD * DD
                                     : Wroot + (size_t)l * DD * DD;
        for (int k8 = 0; k8 < 32; ++k8)
            tl[k8][t] = src[(size_t)(kt * 32 + k8) * DD + t];
        __syncthreads();
        #pragma unroll
        for (int i = 0; i < 4; ++i) {
            int o = i * 256 + t;                 // o = nt8*128 + ks2*64 + fl
            int fl = o & 63, ks2 = (o >> 6) & 1, nt8 = o >> 7;
            int n = nt8 * 32 + (fl & 31);
            int kb = ks2 * 16 + (fl >> 5) * 8;
            unsigned d0 = pk2(tl[kb + 0][n], tl[kb + 1][n]);
            unsigned d1 = pk2(tl[kb + 2][n], tl[kb + 3][n]);
            unsigned d2 = pk2(tl[kb + 4][n], tl[kb + 5][n]);
            unsigned d3 = pk2(tl[kb + 6][n], tl[kb + 7][n]);
            *(uint4*)(Wf + (((size_t)ls * 8 + kt) * 1024 + o) * 8) =
                make_uint4(d0, d1, d2, d3);
        }
    } else {
        int idx = (blockIdx.x - 8 * LL * 9) * 256 + t;   // int4 granules
        int tot = bc * BUCKETS / 4;
        if (idx < tot) ((int4*)counts)[idx] = make_int4(0, 0, 0, 0);
    }
}

// ---------------------------------------------------------------------------
// prep1: (a) gather x0 = bf16(emb[nodes]) (bc*512 blocks)
//        (b) counts[bb][r][dst] += 1 per edge (bc*128 blocks)
// ---------------------------------------------------------------------------
__global__ __launch_bounds__(256) void prep1(const int* __restrict__ nodes,
                                             const float* __restrict__ emb,
                                             u16* __restrict__ x0,
                                             const int* __restrict__ edges,
                                             const int* __restrict__ types,
                                             int* __restrict__ counts,
                                             int b0, int bc)
{
    int ng = bc * 512;
    if ((int)blockIdx.x < ng) {
        int t = blockIdx.x * 256 + threadIdx.x;
        int lane = t & 63;
        int row = t >> 6;
        int bb = row / NN;
        int n  = row - bb * NN;
        int v  = nodes[(size_t)(b0 + bb) * NN + n];
        float4 val = *((const float4*)(emb + (size_t)v * DD) + lane);
        ushort4 o;
        o.x = f2bf(val.x); o.y = f2bf(val.y); o.z = f2bf(val.z); o.w = f2bf(val.w);
        *((ushort4*)(x0 + (size_t)row * DD) + lane) = o;
    } else {
        int t = (blockIdx.x - ng) * 256 + threadIdx.x;
        int bb = t / EE;
        int e  = t - bb * EE;
        const int* eb = edges + (size_t)(b0 + bb) * 2 * EE;
        int dst = eb[EE + e];
        int r   = types[(size_t)(b0 + bb) * EE + e];
        atomicAdd(&counts[((size_t)bb * RR + r) * NN + dst], 1);
    }
}

// ---------------------------------------------------------------------------
// scan2: per-batch exclusive scan of counts (16384 buckets) -> offsets+cursor,
// plus invdeg[bb][n] = 1/max(sum_r counts, 1). One block per batch.
// ---------------------------------------------------------------------------
__global__ __launch_bounds__(256) void scan2_k(const int* __restrict__ counts,
                                               int* __restrict__ offsets,
                                               int* __restrict__ cursor,
                                               float* __restrict__ invdeg)
{
    int bb = blockIdx.x;
    int tid = threadIdx.x;
    size_t base = (size_t)bb * BUCKETS;
    __shared__ int sums[256];

    int tot = 0;
    #pragma unroll 4
    for (int i = 0; i < 64; ++i) tot += counts[base + tid * 64 + i];
    sums[tid] = tot;
    __syncthreads();
    for (int off = 1; off < 256; off <<= 1) {
        int v = (tid >= off) ? sums[tid - off] : 0;
        __syncthreads();
        sums[tid] += v;
        __syncthreads();
    }
    int run = sums[tid] - tot;
    for (int i = 0; i < 64; ++i) {
        size_t idx = base + tid * 64 + i;
        offsets[idx] = run;
        cursor[idx]  = run;
        run += counts[idx];
    }
    // invdeg: thread handles 8 consecutive n
    #pragma unroll
    for (int i = 0; i < 8; ++i) {
        int n = tid * 8 + i;
        int d = 0;
        #pragma unroll
        for (int r = 0; r < RR; ++r)
            d += counts[base + (size_t)r * NN + n];
        invdeg[(size_t)bb * NN + n] = 1.0f / fmaxf((float)d, 1.0f);
    }
}

// ---------------------------------------------------------------------------
// place each edge's src into its bucket slot
// ---------------------------------------------------------------------------
__global__ __launch_bounds__(256) void permute_k(const int* __restrict__ edges,
                                                 const int* __restrict__ types,
                                                 int* __restrict__ cursor,
                                                 int* __restrict__ edgeSrc,
                                                 int b0, int bc)
{
    int t = blockIdx.x * 256 + threadIdx.x;
    int bb = t / EE;
    int e  = t - bb * EE;
    const int* eb = edges + (size_t)(b0 + bb) * 2 * EE;
    int src = eb[e];
    int dst = eb[EE + e];
    int r   = types[(size_t)(b0 + bb) * EE + e];
    int pos = atomicAdd(&cursor[((size_t)bb * RR + r) * NN + dst], 1);
    edgeSrc[(size_t)bb * EE + pos] = src;
}

// ---------------------------------------------------------------------------
// build one segment's A-tile (64 rows x 256 k, bf16, MFMA-frag layout with
// ks-rotation) into LDS buffer A. 64 x 16-lane groups, ONE row per group.
// Thread (j16) covers k-octets ks0=j16>>1 and ks0+8, data-half lh2=j16&1.
// ---------------------------------------------------------------------------
__device__ __forceinline__ void build_seg(int seg, u16* A,
                                          const int* sStart, const int* sCnt,
                                          const int* es, const u16* xb, int m0,
                                          int gid, int j16, int ks0, int lh2)
{
    int row = gid;               // 0..63
    unsigned w0, w1, w2, w3, w4, w5, w6, w7;
    if (seg < 8) {
        f32x2 a[8];
        #pragma unroll
        for (int e = 0; e < 8; ++e) { a[e].x = 0.f; a[e].y = 0.f; }
        int start = sStart[seg * TM + row];
        int cnt   = sCnt[seg * TM + row];
        const int* ep = es + start;
        int jj = 0;
        for (; jj + 2 <= cnt; jj += 2) {
            int s0 = ep[jj], s1 = ep[jj + 1];
            const u16* xr0 = xb + (size_t)s0 * DD;
            const u16* xr1 = xb + (size_t)s1 * DD;
            uint4 p0 = *(const uint4*)(xr0 + j16 * 8);
            uint4 p1 = *(const uint4*)(xr0 + 128 + j16 * 8);
            uint4 q0 = *(const uint4*)(xr1 + j16 * 8);
            uint4 q1 = *(const uint4*)(xr1 + 128 + j16 * 8);
            acc8pk(a, p0, p1);
            acc8pk(a, q0, q1);
        }
        if (jj < cnt) {
            const u16* xr0 = xb + (size_t)ep[jj] * DD;
            uint4 p0 = *(const uint4*)(xr0 + j16 * 8);
            uint4 p1 = *(const uint4*)(xr0 + 128 + j16 * 8);
            acc8pk(a, p0, p1);
        }
        w0 = pk2(a[0].x, a[0].y); w1 = pk2(a[1].x, a[1].y);
        w2 = pk2(a[2].x, a[2].y); w3 = pk2(a[3].x, a[3].y);
        w4 = pk2(a[4].x, a[4].y); w5 = pk2(a[5].x, a[5].y);
        w6 = pk2(a[6].x, a[6].y); w7 = pk2(a[7].x, a[7].y);
    } else {
        // root segment: A = x rows (already bf16 — direct copy)
        const u16* xr = xb + (size_t)(m0 + row) * DD;
        uint4 p0 = *(const uint4*)(xr + j16 * 8);
        uint4 p1 = *(const uint4*)(xr + 128 + j16 * 8);
        w0 = p0.x; w1 = p0.y; w2 = p0.z; w3 = p0.w;
        w4 = p1.x; w5 = p1.y; w6 = p1.z; w7 = p1.w;
    }
    int mt = row >> 5, m31 = row & 31;
    int flw = m31 + 32 * lh2;
    int c0 = ((mt * 16 + ks0) * 64 + ((flw + ks0) & 63)) * 8;
    int c1 = ((mt * 16 + ks0 + 8) * 64 + ((flw + ks0 + 8) & 63)) * 8;
    *(uint4*)&A[c0] = make_uint4(w0, w1, w2, w3);
    *(uint4*)&A[c1] = make_uint4(w4, w5, w6, w7);
}

// ---------------------------------------------------------------------------
// FUSED agg + GEMM, double-buffered A (2 x 32 KB), 1 barrier/segment.
// Block: 64 m-rows x 256 n, 1024 threads (16 waves). Wave (wm, wn):
// wm = m-half (32 rows), wn = n-slice (32 cols) -> one fx16 acc per wave
// (16 VGPR, enables the 64-VGPR cap). Grid 512 blocks = 2 blocks/CU ->
// 32 waves/CU (CU max; R5 was grid-limited to 16). Builder: 64 groups of
// 16 lanes, one row each. wm-pair waves read identical B addresses -> L1.
// XCD swizzle keeps each batch's x in one XCD's L2.
// ---------------------------------------------------------------------------
template <int WRITE_BF16>
__global__ __launch_bounds__(1024, 8) void rgcn_fused(
    const int* __restrict__ offsets, const int* __restrict__ counts,
    const int* __restrict__ edgeSrc, const u16* __restrict__ xin,
    const u16* __restrict__ Wf,      // this layer's frag weights: [9][8][1024][8]
    const float* __restrict__ bias, const float* __restrict__ invdeg,
    float* __restrict__ outF, u16* __restrict__ outH, int relu, int bc)
{
    __shared__ __align__(16) u16 Af[2][16384];   // 2 x 32 KB double buffer
    __shared__ float sInv[TM];
    __shared__ int sStart[8 * TM], sCnt[8 * TM];

    int t = threadIdx.x;
    int fl = t & 63;
    int wid = t >> 6;            // wave id: wn = wid&7 (n-slice), wm = wid>>3
    int wn = wid & 7, wm = wid >> 3;
    int bid = blockIdx.x;
    int bb, mt0;
    if (bc == 16) {              // XCD swizzle: batch pinned to one XCD
        bb  = (bid & 7) * 2 + ((bid >> 3) & 1);
        mt0 = bid >> 4;
    } else {
        bb  = bid >> 5;
        mt0 = bid & 31;
    }
    int m0 = mt0 * TM;

    // preload bucket meta: one bucket per thread for t<512 (8 rel x 64 rows)
    if (t < 512) {
        int g = ((bb * RR + (t >> 6)) * NN) + m0 + (t & 63);
        sStart[t] = offsets[g];
        sCnt[t]   = counts[g];
    }
    if (t < TM) sInv[t] = invdeg[(size_t)bb * NN + m0 + t];

    const u16* xb = xin + (size_t)bb * NN * DD;
    const int* es = edgeSrc + (size_t)bb * EE;

    // A-build coords: 64 groups of 16 lanes; group handles 1 row
    int gid = t >> 4;
    int j16 = t & 15;
    int ks0 = j16 >> 1;
    int lh2 = j16 & 1;
    int lh = fl >> 5;            // acc row mapping

    fx16 acc;
    #pragma unroll
    for (int e = 0; e < 16; ++e) acc[e] = 0.0f;

    __syncthreads();             // meta visible
    build_seg(0, Af[0], sStart, sCnt, es, xb, m0, gid, j16, ks0, lh2);
    __syncthreads();

    for (int seg = 0; seg < 9; ++seg) {
        // build next segment into the other buffer (overlaps this seg's MFMA
        // in-stream and across the 32 resident waves/CU)
        if (seg < 8)
            build_seg(seg + 1, Af[(seg + 1) & 1], sStart, sCnt, es, xb, m0,
                      gid, j16, ks0, lh2);

        if (seg == 8) {
            // normalize aggregation by degree before the root term
            #pragma unroll
            for (int r = 0; r < 16; ++r) {
                int rl = wm * 32 + (r & 3) + 8 * (r >> 2) + 4 * lh;
                acc[r] *= sInv[rl];
            }
        }

        const u16* Wseg = Wf + (size_t)seg * 65536;
        const u16* A = Af[seg & 1];
        #pragma unroll 2
        for (int kt = 0; kt < 8; ++kt) {
            bfx8 bfr[2], af[2];
            #pragma unroll
            for (int ks2 = 0; ks2 < 2; ++ks2) {
                int ksA = kt * 2 + ks2;
                bfr[ks2] = *(const bfx8*)(Wseg + (size_t)kt * 8192 + wn * 1024
                                          + ks2 * 512 + fl * 8);
                af[ks2] = *(const bfx8*)&A[((wm * 16 + ksA) * 64 + ((fl + ksA) & 63)) * 8];
            }
            #pragma unroll
            for (int ks2 = 0; ks2 < 2; ++ks2)
                acc = __builtin_amdgcn_mfma_f32_32x32x16_bf16(af[ks2], bfr[ks2], acc, 0, 0, 0);
        }
        __syncthreads();
    }

    // ---- epilogue ----
    int col = wn * 32 + (fl & 31);
    float bv = bias[col];
    #pragma unroll
    for (int r = 0; r < 16; ++r) {
        int row = m0 + wm * 32 + (r & 3) + 8 * (r >> 2) + 4 * lh;
        float v = acc[r] + bv;
        if (relu) v = fmaxf(v, 0.0f);
        if (WRITE_BF16)
            outH[((size_t)bb * NN + row) * DD + col] = f2bf(v);
        else
            outF[((size_t)bb * NN + row) * DD + col] = v;
    }
}

// ---------------------------------------------------------------------------
extern "C" void kernel_launch(void* const* d_in, const int* in_sizes, int n_in,
                              void* d_out, int out_size, void* d_ws, size_t ws_size,
                              hipStream_t stream)
{
    const int*   nodes = (const int*)d_in[0];
    const int*   edges = (const int*)d_in[1];
    const int*   types = (const int*)d_in[2];
    const float* emb   = (const float*)d_in[3];
    const float* W     = (const float*)d_in[4];
    const float* Wroot = (const float*)d_in[5];
    const float* bias  = (const float*)d_in[6];
    float* out = (float*)d_out;

    const size_t wfElems = (size_t)LL * 9 * 8 * 1024 * 8;
    const size_t fixedBytes = wfElems * sizeof(u16);
    const size_t perBatchBytes =
        2 * (size_t)NN * DD * sizeof(u16) + (size_t)NN * sizeof(float) +
        (3 * (size_t)BUCKETS + EE) * sizeof(int);
    int BC = (int)((ws_size - fixedBytes) / perBatchBytes);
    if (BC > BB) BC = BB;
    if (BC < 1) BC = 1;

    u16* Wf      = (u16*)d_ws;
    u16* x0      = Wf + wfElems;
    u16* x1      = x0 + (size_t)BC * NN * DD;
    float* invdeg = (float*)(x1 + (size_t)BC * NN * DD);
    int* counts  = (int*)(invdeg + (size_t)BC * NN);
    int* offsets = counts + (size_t)BC * BUCKETS;
    int* cursor  = offsets + (size_t)BC * BUCKETS;
    int* edgeSrc = cursor + (size_t)BC * BUCKETS;

    for (int b0 = 0; b0 < BB; b0 += BC) {
        int bc = BB - b0 < BC ? BB - b0 : BC;

        int zeroBlocks = (bc * BUCKETS / 4 + 255) / 256;
        prep0<<<8 * LL * 9 + zeroBlocks, 256, 0, stream>>>(W, Wroot, Wf, counts, bc);
        prep1<<<bc * 640, 256, 0, stream>>>(nodes, emb, x0, edges, types, counts, b0, bc);
        scan2_k<<<bc, 256, 0, stream>>>(counts, offsets, cursor, invdeg);
        permute_k<<<bc * 128, 256, 0, stream>>>(edges, types, cursor, edgeSrc, b0, bc);

        for (int l = 0; l < LL; ++l) {
            const u16* xin = (l == 0) ? x0 : x1;
            const u16* Wfl = Wf + (size_t)l * 9 * 65536;
            if (l == 0)
                rgcn_fused<1><<<bc * 32, 1024, 0, stream>>>(offsets, counts, edgeSrc,
                    xin, Wfl, bias + (size_t)l * DD, invdeg, nullptr, x1, 1, bc);
            else
                rgcn_fused<0><<<bc * 32, 1024, 0, stream>>>(offsets, counts, edgeSrc,
                    xin, Wfl, bias + (size_t)l * DD, invdeg,
                    out + (size_t)b0 * NN * DD, nullptr, 0, bc);
        }
    }
}

// Round 9
// 293.658 us; speedup vs baseline: 1.9522x; 1.9522x over previous
//
#include <hip/hip_runtime.h>
#include <hip/hip_bf16.h>

// Problem constants (match reference setup_inputs)
#define BB 16
#define NN 2048
#define EE 32768
#define DD 256
#define RR 8
#define LL 2
#define BUCKETS (RR * NN)   // 16384 buckets per batch
#define TM 64               // GEMM m-tile

typedef unsigned short u16;
typedef __attribute__((__ext_vector_type__(8))) __bf16 bfx8;   // MFMA A/B frag
typedef __attribute__((__ext_vector_type__(16))) float fx16;   // MFMA acc
typedef __attribute__((__ext_vector_type__(2))) float f32x2;   // v_pk_add_f32

__device__ __forceinline__ float blo(unsigned u){ union{unsigned x;float f;}c; c.x=u<<16; return c.f; }
__device__ __forceinline__ float bhi(unsigned u){ union{unsigned x;float f;}c; c.x=u&0xffff0000u; return c.f; }
// HW packed convert (v_cvt_pk_bf16_f32 on gfx950, RNE) — replaces 10-inst sw RNE
__device__ __forceinline__ unsigned pk2(float a, float b){
    union { __hip_bfloat162 h; unsigned u; } c;
    c.h = __float22bfloat162_rn(make_float2(a, b));
    return c.u;
}
__device__ __forceinline__ u16 f2bf(float f){
    union { __hip_bfloat16 h; u16 u; } c;
    c.h = __float2bfloat16(f);
    return c.u;
}
// packed accumulate: 16 unpack + 8 v_pk_add_f32 per 16 values (was 16+16)
__device__ __forceinline__ void acc8pk(f32x2* a, uint4 p0, uint4 p1) {
    f32x2 v;
    v.x=blo(p0.x); v.y=bhi(p0.x); a[0]+=v;
    v.x=blo(p0.y); v.y=bhi(p0.y); a[1]+=v;
    v.x=blo(p0.z); v.y=bhi(p0.z); a[2]+=v;
    v.x=blo(p0.w); v.y=bhi(p0.w); a[3]+=v;
    v.x=blo(p1.x); v.y=bhi(p1.x); a[4]+=v;
    v.x=blo(p1.y); v.y=bhi(p1.y); a[5]+=v;
    v.x=blo(p1.z); v.y=bhi(p1.z); a[6]+=v;
    v.x=blo(p1.w); v.y=bhi(p1.w); a[7]+=v;
}

// ---------------------------------------------------------------------------
// prep0: (a) weight prep into MFMA-B fragment order (144 blocks)
//        Wf[ls][kt(8)][nt8(8)][ks2(2)][fl(64)][e(8)] bf16,
//        n = nt8*32+(fl&31), k = kt*32+ks2*16+(fl>>5)*8+e, val = Wsrc[k][n]
//        (b) zero counts (remaining blocks)
// ---------------------------------------------------------------------------
__global__ __launch_bounds__(256) void prep0(const float* __restrict__ W,
                                             const float* __restrict__ Wroot,
                                             u16* __restrict__ Wf,
                                             int* __restrict__ counts, int bc)
{
    int t = threadIdx.x;
    if (blockIdx.x < 8 * LL * 9) {
        __shared__ float tl[32][257];   // [k][n], padded
        int kt = blockIdx.x & 7, ls = blockIdx.x >> 3;
        int l = ls / 9, seg = ls - l * 9;
        const float* src = (seg < 8) ? W + (size_t)(l * RR + seg) * DD * DD
                                     : Wroot + (size_t)l * DD * DD;
        for (int k8 = 0; k8 < 32; ++k8)
            tl[k8][t] = src[(size_t)(kt * 32 + k8) * DD + t];
        __syncthreads();
        #pragma unroll
        for (int i = 0; i < 4; ++i) {
            int o = i * 256 + t;                 // o = nt8*128 + ks2*64 + fl
            int fl = o & 63, ks2 = (o >> 6) & 1, nt8 = o >> 7;
            int n = nt8 * 32 + (fl & 31);
            int kb = ks2 * 16 + (fl >> 5) * 8;
            unsigned d0 = pk2(tl[kb + 0][n], tl[kb + 1][n]);
            unsigned d1 = pk2(tl[kb + 2][n], tl[kb + 3][n]);
            unsigned d2 = pk2(tl[kb + 4][n], tl[kb + 5][n]);
            unsigned d3 = pk2(tl[kb + 6][n], tl[kb + 7][n]);
            *(uint4*)(Wf + (((size_t)ls * 8 + kt) * 1024 + o) * 8) =
                make_uint4(d0, d1, d2, d3);
        }
    } else {
        int idx = (blockIdx.x - 8 * LL * 9) * 256 + t;   // int4 granules
        int tot = bc * BUCKETS / 4;
        if (idx < tot) ((int4*)counts)[idx] = make_int4(0, 0, 0, 0);
    }
}

// ---------------------------------------------------------------------------
// prep1: (a) gather x0 = bf16(emb[nodes]) (bc*512 blocks)
//        (b) counts[bb][r][dst] += 1 per edge (bc*128 blocks)
// ---------------------------------------------------------------------------
__global__ __launch_bounds__(256) void prep1(const int* __restrict__ nodes,
                                             const float* __restrict__ emb,
                                             u16* __restrict__ x0,
                                             const int* __restrict__ edges,
                                             const int* __restrict__ types,
                                             int* __restrict__ counts,
                                             int b0, int bc)
{
    int ng = bc * 512;
    if ((int)blockIdx.x < ng) {
        int t = blockIdx.x * 256 + threadIdx.x;
        int lane = t & 63;
        int row = t >> 6;
        int bb = row / NN;
        int n  = row - bb * NN;
        int v  = nodes[(size_t)(b0 + bb) * NN + n];
        float4 val = *((const float4*)(emb + (size_t)v * DD) + lane);
        uint2 o = make_uint2(pk2(val.x, val.y), pk2(val.z, val.w));
        *((uint2*)(x0 + (size_t)row * DD) + lane) = o;
    } else {
        int t = (blockIdx.x - ng) * 256 + threadIdx.x;
        int bb = t / EE;
        int e  = t - bb * EE;
        const int* eb = edges + (size_t)(b0 + bb) * 2 * EE;
        int dst = eb[EE + e];
        int r   = types[(size_t)(b0 + bb) * EE + e];
        atomicAdd(&counts[((size_t)bb * RR + r) * NN + dst], 1);
    }
}

// ---------------------------------------------------------------------------
// scan2: per-batch exclusive scan of counts (16384 buckets) -> offsets+cursor,
// plus invdeg[bb][n] = 1/max(sum_r counts, 1). One block per batch.
// ---------------------------------------------------------------------------
__global__ __launch_bounds__(256) void scan2_k(const int* __restrict__ counts,
                                               int* __restrict__ offsets,
                                               int* __restrict__ cursor,
                                               float* __restrict__ invdeg)
{
    int bb = blockIdx.x;
    int tid = threadIdx.x;
    size_t base = (size_t)bb * BUCKETS;
    __shared__ int sums[256];

    int tot = 0;
    #pragma unroll 4
    for (int i = 0; i < 64; ++i) tot += counts[base + tid * 64 + i];
    sums[tid] = tot;
    __syncthreads();
    for (int off = 1; off < 256; off <<= 1) {
        int v = (tid >= off) ? sums[tid - off] : 0;
        __syncthreads();
        sums[tid] += v;
        __syncthreads();
    }
    int run = sums[tid] - tot;
    for (int i = 0; i < 64; ++i) {
        size_t idx = base + tid * 64 + i;
        offsets[idx] = run;
        cursor[idx]  = run;
        run += counts[idx];
    }
    // invdeg: thread handles 8 consecutive n
    #pragma unroll
    for (int i = 0; i < 8; ++i) {
        int n = tid * 8 + i;
        int d = 0;
        #pragma unroll
        for (int r = 0; r < RR; ++r)
            d += counts[base + (size_t)r * NN + n];
        invdeg[(size_t)bb * NN + n] = 1.0f / fmaxf((float)d, 1.0f);
    }
}

// ---------------------------------------------------------------------------
// place each edge's src into its bucket slot
// ---------------------------------------------------------------------------
__global__ __launch_bounds__(256) void permute_k(const int* __restrict__ edges,
                                                 const int* __restrict__ types,
                                                 int* __restrict__ cursor,
                                                 int* __restrict__ edgeSrc,
                                                 int b0, int bc)
{
    int t = blockIdx.x * 256 + threadIdx.x;
    int bb = t / EE;
    int e  = t - bb * EE;
    const int* eb = edges + (size_t)(b0 + bb) * 2 * EE;
    int src = eb[e];
    int dst = eb[EE + e];
    int r   = types[(size_t)(b0 + bb) * EE + e];
    int pos = atomicAdd(&cursor[((size_t)bb * RR + r) * NN + dst], 1);
    edgeSrc[(size_t)bb * EE + pos] = src;
}

// ---------------------------------------------------------------------------
// build one segment's A-tile (64 rows x 256 k, bf16, MFMA-frag layout with
// ks-rotation) into LDS. 32 x 16-lane groups, 2 rows per group (R5 structure:
// best measured MLP). Packed f32x2 accumulate + HW bf16 pack-convert.
// ---------------------------------------------------------------------------
__device__ __forceinline__ void build_seg(int seg, u16* A,
                                          const int* sStart, const int* sCnt,
                                          const int* es, const u16* xb, int m0,
                                          int gid, int j16, int ks0, int lh2)
{
    #pragma unroll
    for (int rr = 0; rr < 2; ++rr) {
        int row = gid * 2 + rr;
        int mt = row >> 5, m31 = row & 31;
        int flw = m31 + 32 * lh2;
        unsigned w0, w1, w2, w3, w4, w5, w6, w7;
        if (seg < 8) {
            f32x2 a[8];
            #pragma unroll
            for (int e = 0; e < 8; ++e) { a[e].x = 0.f; a[e].y = 0.f; }
            int start = sStart[seg * TM + row];
            int cnt   = sCnt[seg * TM + row];
            const int* ep = es + start;
            int jj = 0;
            for (; jj + 2 <= cnt; jj += 2) {
                int s0 = ep[jj], s1 = ep[jj + 1];
                const u16* xr0 = xb + (size_t)s0 * DD;
                const u16* xr1 = xb + (size_t)s1 * DD;
                uint4 p0 = *(const uint4*)(xr0 + j16 * 8);
                uint4 p1 = *(const uint4*)(xr0 + 128 + j16 * 8);
                uint4 q0 = *(const uint4*)(xr1 + j16 * 8);
                uint4 q1 = *(const uint4*)(xr1 + 128 + j16 * 8);
                acc8pk(a, p0, p1);
                acc8pk(a, q0, q1);
            }
            if (jj < cnt) {
                const u16* xr0 = xb + (size_t)ep[jj] * DD;
                uint4 p0 = *(const uint4*)(xr0 + j16 * 8);
                uint4 p1 = *(const uint4*)(xr0 + 128 + j16 * 8);
                acc8pk(a, p0, p1);
            }
            w0 = pk2(a[0].x, a[0].y); w1 = pk2(a[1].x, a[1].y);
            w2 = pk2(a[2].x, a[2].y); w3 = pk2(a[3].x, a[3].y);
            w4 = pk2(a[4].x, a[4].y); w5 = pk2(a[5].x, a[5].y);
            w6 = pk2(a[6].x, a[6].y); w7 = pk2(a[7].x, a[7].y);
        } else {
            // root segment: A = x rows (already bf16 — direct copy)
            const u16* xr = xb + (size_t)(m0 + row) * DD;
            uint4 p0 = *(const uint4*)(xr + j16 * 8);
            uint4 p1 = *(const uint4*)(xr + 128 + j16 * 8);
            w0 = p0.x; w1 = p0.y; w2 = p0.z; w3 = p0.w;
            w4 = p1.x; w5 = p1.y; w6 = p1.z; w7 = p1.w;
        }
        int c0 = ((mt * 16 + ks0) * 64 + ((flw + ks0) & 63)) * 8;
        int c1 = ((mt * 16 + ks0 + 8) * 64 + ((flw + ks0 + 8) & 63)) * 8;
        *(uint4*)&A[c0] = make_uint4(w0, w1, w2, w3);
        *(uint4*)&A[c1] = make_uint4(w4, w5, w6, w7);
    }
}

// ---------------------------------------------------------------------------
// FUSED agg + GEMM, double-buffered A (2 x 32 KB), 1 barrier/segment.
// Block: 64 m-rows x 256 n, 512 threads (8 waves, wave = 32-col n-slice,
// 2 m-tiles per wave -> acc[2]). Grid 512 = 2 blocks/CU, 16 waves/CU.
// R5 structure — measured best of {R5,R6,R7,R8}; see round journal.
// XCD swizzle keeps each batch's x in one XCD's L2.
// ---------------------------------------------------------------------------
template <int WRITE_BF16>
__global__ __launch_bounds__(512, 4) void rgcn_fused(
    const int* __restrict__ offsets, const int* __restrict__ counts,
    const int* __restrict__ edgeSrc, const u16* __restrict__ xin,
    const u16* __restrict__ Wf,      // this layer's frag weights: [9][8][1024][8]
    const float* __restrict__ bias, const float* __restrict__ invdeg,
    float* __restrict__ outF, u16* __restrict__ outH, int relu, int bc)
{
    __shared__ __align__(16) u16 Af[2][16384];   // 2 x 32 KB double buffer
    __shared__ float sInv[TM];
    __shared__ int sStart[8 * TM], sCnt[8 * TM];

    int t = threadIdx.x;
    int fl = t & 63;
    int wid = t >> 6;            // wave id = n-slice (32 cols each)
    int bid = blockIdx.x;
    int bb, mt0;
    if (bc == 16) {              // XCD swizzle: batch pinned to one XCD
        bb  = (bid & 7) * 2 + ((bid >> 3) & 1);
        mt0 = bid >> 4;
    } else {
        bb  = bid >> 5;
        mt0 = bid & 31;
    }
    int m0 = mt0 * TM;

    // preload bucket meta: exactly one bucket per thread (8 rel x 64 rows)
    {
        int r = t >> 6, row = t & 63;
        int g = ((bb * RR + r) * NN) + m0 + row;
        sStart[t] = offsets[g];
        sCnt[t]   = counts[g];
    }
    if (t < TM) sInv[t] = invdeg[(size_t)bb * NN + m0 + t];

    const u16* xb = xin + (size_t)bb * NN * DD;
    const int* es = edgeSrc + (size_t)bb * EE;

    // A-build coords: 32 groups of 16 lanes; group handles 2 rows
    int gid = t >> 4;
    int j16 = t & 15;
    int ks0 = j16 >> 1;
    int lh2 = j16 & 1;
    int lh = fl >> 5;            // acc row mapping

    fx16 acc[2];
    #pragma unroll
    for (int mt = 0; mt < 2; ++mt)
        #pragma unroll
        for (int e = 0; e < 16; ++e) acc[mt][e] = 0.0f;

    __syncthreads();             // meta visible
    build_seg(0, Af[0], sStart, sCnt, es, xb, m0, gid, j16, ks0, lh2);
    __syncthreads();

    for (int seg = 0; seg < 9; ++seg) {
        // build next segment into the other buffer (overlaps this seg's MFMA
        // in-stream and across the 16 resident waves/CU)
        if (seg < 8)
            build_seg(seg + 1, Af[(seg + 1) & 1], sStart, sCnt, es, xb, m0,
                      gid, j16, ks0, lh2);

        if (seg == 8) {
            // normalize aggregation by degree before the root term
            #pragma unroll
            for (int mt = 0; mt < 2; ++mt)
                #pragma unroll
                for (int r = 0; r < 16; ++r) {
                    int rl = mt * 32 + (r & 3) + 8 * (r >> 2) + 4 * lh;
                    acc[mt][r] *= sInv[rl];
                }
        }

        const u16* Wseg = Wf + (size_t)seg * 65536;
        const u16* A = Af[seg & 1];
        #pragma unroll 2
        for (int kt = 0; kt < 8; ++kt) {
            bfx8 bfr[2], af[2][2];
            #pragma unroll
            for (int ks2 = 0; ks2 < 2; ++ks2) {
                int ksA = kt * 2 + ks2;
                bfr[ks2] = *(const bfx8*)(Wseg + (size_t)kt * 8192 + wid * 1024
                                          + ks2 * 512 + fl * 8);
                af[0][ks2] = *(const bfx8*)&A[((0  + ksA) * 64 + ((fl + ksA) & 63)) * 8];
                af[1][ks2] = *(const bfx8*)&A[((16 + ksA) * 64 + ((fl + ksA) & 63)) * 8];
            }
            #pragma unroll
            for (int ks2 = 0; ks2 < 2; ++ks2) {
                acc[0] = __builtin_amdgcn_mfma_f32_32x32x16_bf16(af[0][ks2], bfr[ks2], acc[0], 0, 0, 0);
                acc[1] = __builtin_amdgcn_mfma_f32_32x32x16_bf16(af[1][ks2], bfr[ks2], acc[1], 0, 0, 0);
            }
        }
        __syncthreads();
    }

    // ---- epilogue ----
    int col = wid * 32 + (fl & 31);
    float bv = bias[col];
    #pragma unroll
    for (int mt = 0; mt < 2; ++mt)
        #pragma unroll
        for (int r = 0; r < 16; ++r) {
            int row = m0 + mt * 32 + (r & 3) + 8 * (r >> 2) + 4 * lh;
            float v = acc[mt][r] + bv;
            if (relu) v = fmaxf(v, 0.0f);
            if (WRITE_BF16)
                outH[((size_t)bb * NN + row) * DD + col] = f2bf(v);
            else
                outF[((size_t)bb * NN + row) * DD + col] = v;
        }
}

// ---------------------------------------------------------------------------
extern "C" void kernel_launch(void* const* d_in, const int* in_sizes, int n_in,
                              void* d_out, int out_size, void* d_ws, size_t ws_size,
                              hipStream_t stream)
{
    const int*   nodes = (const int*)d_in[0];
    const int*   edges = (const int*)d_in[1];
    const int*   types = (const int*)d_in[2];
    const float* emb   = (const float*)d_in[3];
    const float* W     = (const float*)d_in[4];
    const float* Wroot = (const float*)d_in[5];
    const float* bias  = (const float*)d_in[6];
    float* out = (float*)d_out;

    const size_t wfElems = (size_t)LL * 9 * 8 * 1024 * 8;
    const size_t fixedBytes = wfElems * sizeof(u16);
    const size_t perBatchBytes =
        2 * (size_t)NN * DD * sizeof(u16) + (size_t)NN * sizeof(float) +
        (3 * (size_t)BUCKETS + EE) * sizeof(int);
    int BC = (int)((ws_size - fixedBytes) / perBatchBytes);
    if (BC > BB) BC = BB;
    if (BC < 1) BC = 1;

    u16* Wf      = (u16*)d_ws;
    u16* x0      = Wf + wfElems;
    u16* x1      = x0 + (size_t)BC * NN * DD;
    float* invdeg = (float*)(x1 + (size_t)BC * NN * DD);
    int* counts  = (int*)(invdeg + (size_t)BC * NN);
    int* offsets = counts + (size_t)BC * BUCKETS;
    int* cursor  = offsets + (size_t)BC * BUCKETS;
    int* edgeSrc = cursor + (size_t)BC * BUCKETS;

    for (int b0 = 0; b0 < BB; b0 += BC) {
        int bc = BB - b0 < BC ? BB - b0 : BC;

        int zeroBlocks = (bc * BUCKETS / 4 + 255) / 256;
        prep0<<<8 * LL * 9 + zeroBlocks, 256, 0, stream>>>(W, Wroot, Wf, counts, bc);
        prep1<<<bc * 640, 256, 0, stream>>>(nodes, emb, x0, edges, types, counts, b0, bc);
        scan2_k<<<bc, 256, 0, stream>>>(counts, offsets, cursor, invdeg);
        permute_k<<<bc * 128, 256, 0, stream>>>(edges, types, cursor, edgeSrc, b0, bc);

        for (int l = 0; l < LL; ++l) {
            const u16* xin = (l == 0) ? x0 : x1;
            const u16* Wfl = Wf + (size_t)l * 9 * 65536;
            if (l == 0)
                rgcn_fused<1><<<bc * 32, 512, 0, stream>>>(offsets, counts, edgeSrc,
                    xin, Wfl, bias + (size_t)l * DD, invdeg, nullptr, x1, 1, bc);
            else
                rgcn_fused<0><<<bc * 32, 512, 0, stream>>>(offsets, counts, edgeSrc,
                    xin, Wfl, bias + (size_t)l * DD, invdeg,
                    out + (size_t)b0 * NN * DD, nullptr, 0, bc);
        }
    }
}